// Round 1
// baseline (500.229 us; speedup 1.0000x reference)
//
#include <hip/hip_runtime.h>

#define B_ 256
#define S_ 1024
#define D_ 128
#define H_ 256

typedef short short8 __attribute__((ext_vector_type(8)));
typedef float f32x4 __attribute__((ext_vector_type(4)));

// Cross-kernel small buffers (re-initialized every call by prep/means0/layers).
__device__ unsigned short g_Wb0[H_ * D_];   // bf16 left-half of W0
__device__ unsigned short g_Wb1[H_ * H_];
__device__ unsigned short g_Wb2[H_ * H_];
__device__ float g_mean0[B_ * D_];          // column SUMS of x
__device__ float g_colsum1[B_ * H_];        // fp32 column sums of layer outputs
__device__ float g_colsum2[B_ * H_];

__device__ __forceinline__ unsigned short f2bf(float x) {
    union { float f; unsigned u; } v; v.f = x;
    unsigned r = v.u + 0x7FFFu + ((v.u >> 16) & 1u);
    return (unsigned short)(r >> 16);
}
__device__ __forceinline__ float bf2f(unsigned short h) {
    union { float f; unsigned u; } v; v.u = ((unsigned)h) << 16;
    return v.f;
}
__device__ __forceinline__ float fast_tanh(float x) {
    float e = __builtin_amdgcn_exp2f(x * 2.885390081777927f); // 2*log2(e)
    float r = __builtin_amdgcn_rcpf(1.0f + e);
    return 1.0f - 2.0f * r;
}
__device__ __forceinline__ unsigned cvt_pk_bf16(float lo, float hi) {
    unsigned r;
    asm("v_cvt_pk_bf16_f32 %0, %1, %2" : "=v"(r) : "v"(lo), "v"(hi));
    return r;
}

// ---- prep: convert W left-halves to bf16; zero colsum bufs and out --------
__global__ __launch_bounds__(256) void prep_kernel(
    const float* __restrict__ W0, const float* __restrict__ W1,
    const float* __restrict__ W2, float* __restrict__ out)
{
    int i = blockIdx.x * 256 + threadIdx.x;
    if (i < H_ * D_) { g_Wb0[i] = f2bf(W0[(i >> 7) * 256 + (i & 127)]); return; }
    i -= H_ * D_;
    if (i < H_ * H_) { g_Wb1[i] = f2bf(W1[(i >> 8) * 512 + (i & 255)]); return; }
    i -= H_ * H_;
    if (i < H_ * H_) { g_Wb2[i] = f2bf(W2[(i >> 8) * 512 + (i & 255)]); return; }
    i -= H_ * H_;
    if (i < B_ * H_) { g_colsum1[i] = 0.f; return; }
    i -= B_ * H_;
    if (i < B_ * H_) { g_colsum2[i] = 0.f; return; }
    i -= B_ * H_;
    if (i < B_ * H_) { out[i] = 0.f; return; }
}

// ---- means0: one block per set, column sums of x in fp32, no atomics -------
__global__ __launch_bounds__(1024) void means0_kernel(const float* __restrict__ x)
{
    const int set = blockIdx.x, t = threadIdx.x;
    const int cg = t & 31, rg = t >> 5;               // col-group of 4, row group
    const float* xb = x + (size_t)set * S_ * D_;
    f32x4 s = (f32x4){0.f, 0.f, 0.f, 0.f};
    #pragma unroll 8
    for (int i = 0; i < 32; ++i)
        s += *(const f32x4*)(xb + (rg + i * 32) * D_ + cg * 4);
    __shared__ f32x4 red[32][32];
    red[rg][cg] = s;
    __syncthreads();
    if (t < 32) {
        f32x4 a = red[0][t];
        #pragma unroll
        for (int g = 1; g < 32; ++g) a += red[g][t];
        #pragma unroll
        for (int c = 0; c < 4; ++c) g_mean0[set * D_ + t * 4 + c] = a[c];
    }
}

// ---- layer: grid=512 (2 blocks per set, 512 rows each), 1024 thr / 16 waves
// Wave owns 32 rows -> y-fragments are only 64 VGPRs, total <=128/wave ->
// 4 waves/SIMD (2x occupancy vs previous 64-row-wave version).
// MFMA operands SWAPPED (W = A-operand, y = B-operand): per lane the output is
// one y-row x 4 consecutive out-cols -> cvt_pk_bf16 + 8B dwordx2 stores.
// Column sums: 16-lane shfl reduce -> LDS atomics -> global atomics (the two
// row-half blocks of a set accumulate into prep-zeroed buffers).
template <int LAYER>
__global__ __launch_bounds__(1024, 4) void layer_kernel(
    const float* __restrict__ x, const float* __restrict__ W,
    const float* __restrict__ bias, unsigned short* __restrict__ y,
    float* __restrict__ out)
{
    constexpr int K  = (LAYER == 0) ? D_ : H_;
    constexpr int KS = K / 32;            // 4 or 8 k-steps
    constexpr int SLOTS = K / 8;          // 16B slots per W row
    const int set = blockIdx.x >> 1;
    const int rh  = blockIdx.x & 1;
    const int t = threadIdx.x;
    const int lane = t & 63, wave = t >> 6;
    const int l15 = lane & 15, quad = lane >> 4;

    __shared__ unsigned short W_lds[256 * K];    // 64 / 128 KB
    __shared__ float mean_lds[K];
    __shared__ float c_lds[H_];
    __shared__ float colsum_lds[H_];
    __shared__ float cpart[1024];

    const unsigned short* Wb = (LAYER == 0) ? g_Wb0 : (LAYER == 1) ? g_Wb1 : g_Wb2;
    const float* msrc = (LAYER == 0) ? g_mean0 : (LAYER == 1) ? g_colsum1 : g_colsum2;

    if (t < K)   mean_lds[t] = msrc[set * K + t] * (1.f / S_);
    if (t < H_)  colsum_lds[t] = 0.f;
    __syncthreads();

    // Fill W_lds (bf16, swizzled: 16B slot s of row n stored at s^(n&7)),
    // 4 threads per row.
    {
        const int n = t >> 2, p = t & 3;
        #pragma unroll
        for (int i = 0; i < SLOTS / 4; ++i) {
            const int slot = p * (SLOTS / 4) + i;
            *(uint4*)(&W_lds[n * K + ((slot ^ (n & 7)) * 8)]) =
                *(const uint4*)(&Wb[n * K + slot * 8]);
        }
    }

    // ---- B-fragments (y rows): issue global loads early, c-phase hides them
    const int rowbase = rh * 512 + wave * 32;     // within set
    short8 a[2][KS];
    if (LAYER == 0) {
        const float* xb = x + ((size_t)set * S_ + rowbase) * D_;
        #pragma unroll
        for (int mf = 0; mf < 2; ++mf)
            #pragma unroll
            for (int ks = 0; ks < KS; ++ks) {
                const float* p = xb + (mf * 16 + l15) * D_ + ks * 32 + quad * 8;
                f32x4 v0 = *(const f32x4*)(p);
                f32x4 v1 = *(const f32x4*)(p + 4);
                union { short8 s; unsigned u[4]; } sv;
                sv.u[0] = cvt_pk_bf16(v0[0], v0[1]);
                sv.u[1] = cvt_pk_bf16(v0[2], v0[3]);
                sv.u[2] = cvt_pk_bf16(v1[0], v1[1]);
                sv.u[3] = cvt_pk_bf16(v1[2], v1[3]);
                a[mf][ks] = sv.s;
            }
    } else {
        const unsigned short* yb = y + ((size_t)set * S_ + rowbase) * H_;
        #pragma unroll
        for (int mf = 0; mf < 2; ++mf)
            #pragma unroll
            for (int ks = 0; ks < KS; ++ks)
                a[mf][ks] = *(const short8*)(yb + (mf * 16 + l15) * H_ + ks * 32 + quad * 8);
    }

    // c[j] = b[j] + mean @ (W_right + (W_left - bf16(W_left))).T  (fp32)
    {
        const int j = t >> 2, q = t & 3;
        const float* wl = W + j * 2 * K + q * (K / 4);
        const float* wr = wl + K;
        float acc = 0.f;
        #pragma unroll 4
        for (int k = 0; k < K / 4; k += 4) {
            f32x4 aa = *(const f32x4*)(wl + k);
            f32x4 bb = *(const f32x4*)(wr + k);
            f32x4 m  = *(const f32x4*)(&mean_lds[q * (K / 4) + k]);
            #pragma unroll
            for (int c = 0; c < 4; ++c)
                acc += m[c] * (bb[c] + (aa[c] - bf2f(f2bf(aa[c]))));
        }
        cpart[t] = acc;
    }
    __syncthreads();
    if (t < H_) c_lds[t] = bias[t] + cpart[4 * t] + cpart[4 * t + 1]
                                   + cpart[4 * t + 2] + cpart[4 * t + 3];
    __syncthreads();

    unsigned short* ybase = y + ((size_t)set * S_ + rowbase) * H_;

    for (int nt = 0; nt < 8; ++nt) {              // 32-col n-tiles
        f32x4 acc[2][2];
        #pragma unroll
        for (int i = 0; i < 2; ++i) {
            acc[i][0] = (f32x4){0.f, 0.f, 0.f, 0.f};
            acc[i][1] = (f32x4){0.f, 0.f, 0.f, 0.f};
        }
        const int r0 = (nt * 32 + l15) * K;
        const int r1 = r0 + 16 * K;
        #pragma unroll
        for (int ks = 0; ks < KS; ++ks) {
            const int so = (((ks * 4 + quad) ^ (l15 & 7)) * 8);
            short8 w0 = *(const short8*)(&W_lds[r0 + so]);
            short8 w1 = *(const short8*)(&W_lds[r1 + so]);
            acc[0][0] = __builtin_amdgcn_mfma_f32_16x16x32_bf16(w0, a[0][ks], acc[0][0], 0, 0, 0);
            acc[1][0] = __builtin_amdgcn_mfma_f32_16x16x32_bf16(w0, a[1][ks], acc[1][0], 0, 0, 0);
            acc[0][1] = __builtin_amdgcn_mfma_f32_16x16x32_bf16(w1, a[0][ks], acc[0][1], 0, 0, 0);
            acc[1][1] = __builtin_amdgcn_mfma_f32_16x16x32_bf16(w1, a[1][ks], acc[1][1], 0, 0, 0);
        }
        // epilogue. D layout (swapped operands): lane holds
        // yrow = rowbase + mf*16 + l15, outcols = nt*32 + nf*16 + quad*4 + r
        #pragma unroll
        for (int nf = 0; nf < 2; ++nf) {
            const int colbase = nt * 32 + nf * 16 + quad * 4;
            const f32x4 cv = *(const f32x4*)(&c_lds[colbase]);
            f32x4 cs = (f32x4){0.f, 0.f, 0.f, 0.f};
            #pragma unroll
            for (int mf = 0; mf < 2; ++mf) {
                f32x4 th;
                #pragma unroll
                for (int r = 0; r < 4; ++r)
                    th[r] = fast_tanh(acc[mf][nf][r] + cv[r]);
                cs += th;
                if (LAYER < 2) {
                    uint2 pv;
                    pv.x = cvt_pk_bf16(th[0], th[1]);
                    pv.y = cvt_pk_bf16(th[2], th[3]);
                    *(uint2*)(&ybase[(mf * 16 + l15) * H_ + colbase]) = pv;
                }
            }
            // reduce over the 16 l15 lanes (rows), then one LDS atomic per col
            #pragma unroll
            for (int s = 1; s < 16; s <<= 1) {
                #pragma unroll
                for (int r = 0; r < 4; ++r) cs[r] += __shfl_xor(cs[r], s);
            }
            if (l15 == 0) {
                #pragma unroll
                for (int r = 0; r < 4; ++r)
                    atomicAdd(&colsum_lds[colbase + r], cs[r]);
            }
        }
    }
    __syncthreads();
    if (t < H_) {
        const float v = colsum_lds[t];
        if (LAYER == 2)      atomicAdd(&out[set * H_ + t], v * (1.f / S_));
        else if (LAYER == 1) atomicAdd(&g_colsum2[set * H_ + t], v);
        else                 atomicAdd(&g_colsum1[set * H_ + t], v);
    }
}

extern "C" void kernel_launch(void* const* d_in, const int* in_sizes, int n_in,
                              void* d_out, int out_size, void* d_ws, size_t ws_size,
                              hipStream_t stream) {
    (void)in_sizes; (void)n_in; (void)out_size; (void)ws_size;
    const float* x  = (const float*)d_in[0];
    const float* W0 = (const float*)d_in[1];
    const float* b0 = (const float*)d_in[2];
    const float* W1 = (const float*)d_in[3];
    const float* b1 = (const float*)d_in[4];
    const float* W2 = (const float*)d_in[5];
    const float* b2 = (const float*)d_in[6];
    float* out = (float*)d_out;
    unsigned short* ws = (unsigned short*)d_ws;   // y: [256][1024][256] bf16 = 128 MiB

    prep_kernel<<<dim3(1408), dim3(256), 0, stream>>>(W0, W1, W2, out);
    means0_kernel<<<dim3(256), dim3(1024), 0, stream>>>(x);
    layer_kernel<0><<<dim3(512), dim3(1024), 0, stream>>>(x, W0, b0, ws, out);
    layer_kernel<1><<<dim3(512), dim3(1024), 0, stream>>>(x, W1, b1, ws, out);
    layer_kernel<2><<<dim3(512), dim3(1024), 0, stream>>>(x, W2, b2, ws, out);
}